// Round 6
// baseline (1008.148 us; speedup 1.0000x reference)
//
#include <hip/hip_runtime.h>

typedef unsigned short u16;
typedef __bf16 bf16x8 __attribute__((ext_vector_type(8)));
typedef float f32x4 __attribute__((ext_vector_type(4)));
typedef u16 u16x8 __attribute__((ext_vector_type(8)));

union V8 { u16x8 u; bf16x8 b; };

#define NB 4
#define NS 2048
#define ND 1024
#define NH 16
#define NDK 64
#define LP 80  // padded LDS row stride (u16): 16B-aligned, breaks bank stride

__device__ __forceinline__ u16 f2bf(float f) {
  union { float f; unsigned u; } v; v.f = f;
  return (u16)((v.u + 0x7fffu + ((v.u >> 16) & 1u)) >> 16);  // RNE
}

__device__ __forceinline__ bf16x8 lds_frag(const u16* p) {
  V8 t; t.u = *(const u16x8*)p; return t.b;
}

// Load 8 consecutive elements (as bf16 bits); source fp32 or bf16 (wave-uniform).
__device__ __forceinline__ u16x8 load8(const void* base, size_t elem_off, int isbf) {
  u16x8 r;
  if (isbf) {
    r = *(const u16x8*)((const u16*)base + elem_off);
  } else {
    const float* f = (const float*)base + elem_off;
    const f32x4 lo = *(const f32x4*)f;
    const f32x4 hi = *(const f32x4*)(f + 4);
    for (int j = 0; j < 4; j++) { r[j] = f2bf(lo[j]); r[j + 4] = f2bf(hi[j]); }
  }
  return r;
}

// C = X @ W^T (M=8192, N=1024, K=1024), 128x128 tile, BK=64, 4 waves.
// mode 0/1: RoPE epilogue, bf16 store [B][H][S][DK] (Q, K)
// mode 2:   bf16 store [B][H][S][DK] (V)
// mode 3:   fp32 store row-major [M][N] (final output — d_out is float*)
__global__ __launch_bounds__(256) void gemm_qkv(
    const void* __restrict__ X, const void* __restrict__ W0,
    const void* __restrict__ W1, const void* __restrict__ W2,
    void* __restrict__ O0, void* __restrict__ O1, void* __restrict__ O2,
    const int* __restrict__ tokpos, int modebase, int abf) {
  __shared__ u16 ldsA[128 * LP];
  __shared__ u16 ldsB[128 * LP];
  const int tid = threadIdx.x;
  const int lane = tid & 63;
  const int w = tid >> 6;
  const int quad = lane >> 4;
  const int l15 = lane & 15;
  const int z = blockIdx.z;
  const void* Wp = (z == 0) ? W0 : (z == 1) ? W1 : W2;
  void* Op = (z == 0) ? O0 : (z == 1) ? O1 : O2;
  const int mode = modebase + z;
  const int m0 = blockIdx.x * 128;
  const int n0 = blockIdx.y * 128;
  const int wm = (w >> 1) * 64;
  const int wn = (w & 1) * 64;

  const int srow = tid >> 3;        // 0..31
  const int scol = (tid & 7) * 8;   // 0..56

  f32x4 acc[4][4];
  const f32x4 z4 = {0.f, 0.f, 0.f, 0.f};
  for (int i = 0; i < 4; i++)
    for (int j = 0; j < 4; j++) acc[i][j] = z4;

  for (int k0 = 0; k0 < ND; k0 += 64) {
    u16x8 ar[4], br[4];
    for (int r = 0; r < 4; r++) {
      ar[r] = load8(X, (size_t)(m0 + r * 32 + srow) * ND + k0 + scol, abf);
      br[r] = load8(Wp, (size_t)(n0 + r * 32 + srow) * ND + k0 + scol, 0);
    }
    __syncthreads();  // WAR
    for (int r = 0; r < 4; r++) {
      *(u16x8*)&ldsA[(r * 32 + srow) * LP + scol] = ar[r];
      *(u16x8*)&ldsB[(r * 32 + srow) * LP + scol] = br[r];
    }
    __syncthreads();  // RAW
    for (int kk = 0; kk < 2; kk++) {
      bf16x8 af[4], bfr[4];
      for (int mt = 0; mt < 4; mt++)
        af[mt] = lds_frag(&ldsA[(wm + mt * 16 + l15) * LP + (kk * 4 + quad) * 8]);
      for (int nt = 0; nt < 4; nt++)
        bfr[nt] = lds_frag(&ldsB[(wn + nt * 16 + l15) * LP + (kk * 4 + quad) * 8]);
      for (int mt = 0; mt < 4; mt++)
        for (int nt = 0; nt < 4; nt++)
          acc[mt][nt] = __builtin_amdgcn_mfma_f32_16x16x32_bf16(
              af[mt], bfr[nt], acc[mt][nt], 0, 0, 0);
    }
  }

  // epilogue: C(m_g, n_g): m_g = m0+wm+mt*16+quad*4+r, n_g = n0+wn+nt*16+l15
  for (int nt = 0; nt < 4; nt++) {
    const int n_g = n0 + wn + nt * 16 + l15;
    const int h = n_g >> 6;
    const int dk = n_g & 63;
    const float sgn = (dk & 1) ? 1.f : -1.f;
    float inv_freq = 0.f;
    if (mode < 2)
      inv_freq = __expf(-(float)(dk >> 1) * 0.28782313662425572f);  // ln(1e4)/32
    for (int mt = 0; mt < 4; mt++) {
      const int mb = m0 + wm + mt * 16 + quad * 4;
      for (int r = 0; r < 4; r++) {
        const int m_g = mb + r;
        float v = acc[mt][nt][r];
        if (mode < 2) {
          // RoPE: pair (2i,2i+1) sits in adjacent lanes (dk on lane&15)
          const int s_i = m_g & (NS - 1);
          const float pos = (float)tokpos[s_i];
          const float partner = __shfl_xor(v, 1);
          float sn, cs;
          __sincosf(pos * inv_freq, &sn, &cs);
          v = v * cs + partner * sn * sgn;
        }
        if (mode <= 2) {
          const int b = m_g >> 11;
          const int s_i = m_g & (NS - 1);
          ((u16*)Op)[(size_t)(((b * NH) + h) * NS + s_i) * NDK + dk] = f2bf(v);
        } else {
          ((float*)Op)[(size_t)m_g * ND + n_g] = v;  // d_out is fp32
        }
      }
    }
  }
}

// causal flash attention: 1 block = 64 queries (16/wave), 64-key tiles.
// V transposed into LDS at staging; AO written bf16 row-major [B*S][D].
__global__ __launch_bounds__(256) void attn(const u16* __restrict__ Q,
                                            const u16* __restrict__ Kc,
                                            const u16* __restrict__ Vv,
                                            u16* __restrict__ AO) {
  __shared__ u16 kt[64 * LP];        // [key][dk]
  __shared__ u16 vt[64 * LP];        // [dk][key]
  __shared__ u16 pbuf[4][16 * LP];   // per-wave P: [query][key]
  const int tid = threadIdx.x;
  const int lane = tid & 63;
  const int w = tid >> 6;
  const int quad = lane >> 4;
  const int l15 = lane & 15;
  const int bh = blockIdx.y;
  const int q0 = (gridDim.x - 1 - blockIdx.x) * 64;  // heavy diagonal first

  // Q fragments resident: A[m=lane&15 (query)][k=quad*8+j (dk)]
  const u16* Qb = Q + (size_t)bh * NS * NDK + (size_t)(q0 + w * 16 + l15) * NDK + quad * 8;
  const bf16x8 qf0 = lds_frag(Qb);
  const bf16x8 qf1 = lds_frag(Qb + 32);

  f32x4 oacc[4];
  const f32x4 z4 = {0.f, 0.f, 0.f, 0.f};
  for (int i = 0; i < 4; i++) oacc[i] = z4;
  float mi[4], li[4];
  for (int r = 0; r < 4; r++) { mi[r] = -1e30f; li[r] = 0.f; }

  const int srow = tid >> 3;        // 0..31
  const int scol = (tid & 7) * 8;   // 0..56
  const u16* Kb = Kc + (size_t)bh * NS * NDK;
  const u16* Vb = Vv + (size_t)bh * NS * NDK;
  u16* pw = pbuf[w];

  for (int j0 = 0; j0 <= q0; j0 += 64) {
    u16x8 kreg[2], vreg[2];
    for (int r = 0; r < 2; r++) {
      kreg[r] = *(const u16x8*)(Kb + (size_t)(j0 + r * 32 + srow) * NDK + scol);
      vreg[r] = *(const u16x8*)(Vb + (size_t)(j0 + r * 32 + srow) * NDK + scol);
    }
    __syncthreads();  // WAR
    for (int r = 0; r < 2; r++) {
      *(u16x8*)&kt[(r * 32 + srow) * LP + scol] = kreg[r];
      for (int j = 0; j < 8; j++)                      // transpose V: [dk][key]
        vt[(scol + j) * LP + r * 32 + srow] = vreg[r][j];
    }
    __syncthreads();  // RAW

    // S = Q K^T : D[row=query(quad*4+r)][col=key(l15)] per 16-key tile nt
    f32x4 sa[4];
    for (int i = 0; i < 4; i++) sa[i] = z4;
    for (int kk = 0; kk < 2; kk++) {
      const bf16x8 qf = kk ? qf1 : qf0;
      for (int nt = 0; nt < 4; nt++) {
        const bf16x8 kf = lds_frag(&kt[(nt * 16 + l15) * LP + (kk * 4 + quad) * 8]);
        sa[nt] = __builtin_amdgcn_mfma_f32_16x16x32_bf16(qf, kf, sa[nt], 0, 0, 0);
      }
    }

    const bool diag = (j0 == q0);
    float pv[4][4];
    float rm[4] = {-3e30f, -3e30f, -3e30f, -3e30f};
    for (int nt = 0; nt < 4; nt++) {
      const int kg = j0 + nt * 16 + l15;
      for (int r = 0; r < 4; r++) {
        float s = sa[nt][r] * 0.125f;  // 1/sqrt(64)
        if (diag) {
          const int qg = q0 + w * 16 + quad * 4 + r;
          if (kg > qg) s = -1e30f;
        }
        pv[nt][r] = s;
        rm[r] = fmaxf(rm[r], s);
      }
    }
    for (int r = 0; r < 4; r++) {
      for (int m = 1; m < 16; m <<= 1) rm[r] = fmaxf(rm[r], __shfl_xor(rm[r], m));
      const float mnew = fmaxf(mi[r], rm[r]);
      const float alpha = __expf(mi[r] - mnew);
      mi[r] = mnew;
      li[r] *= alpha;
      for (int nt = 0; nt < 4; nt++) oacc[nt][r] *= alpha;
    }
    float rs[4] = {0.f, 0.f, 0.f, 0.f};
    for (int nt = 0; nt < 4; nt++)
      for (int r = 0; r < 4; r++) {
        const float p = __expf(pv[nt][r] - mi[r]);
        pv[nt][r] = p;
        rs[r] += p;
      }
    for (int r = 0; r < 4; r++) {
      for (int m = 1; m < 16; m <<= 1) rs[r] += __shfl_xor(rs[r], m);
      li[r] += rs[r];
    }

    // P: C-layout -> A-layout via per-wave LDS, ordered by a full barrier
    for (int nt = 0; nt < 4; nt++)
      for (int r = 0; r < 4; r++)
        pw[(quad * 4 + r) * LP + nt * 16 + l15] = f2bf(pv[nt][r]);
    __syncthreads();
    const bf16x8 pf0 = lds_frag(&pw[l15 * LP + quad * 8]);
    const bf16x8 pf1 = lds_frag(&pw[l15 * LP + 32 + quad * 8]);

    // O += P V : B[n=dk (l15)][k=key (quad*8+j)] from transposed vt rows
    for (int nt = 0; nt < 4; nt++) {
      const int rv = nt * 16 + l15;
      const bf16x8 vf0 = lds_frag(&vt[rv * LP + quad * 8]);
      const bf16x8 vf1 = lds_frag(&vt[rv * LP + 32 + quad * 8]);
      oacc[nt] = __builtin_amdgcn_mfma_f32_16x16x32_bf16(pf0, vf0, oacc[nt], 0, 0, 0);
      oacc[nt] = __builtin_amdgcn_mfma_f32_16x16x32_bf16(pf1, vf1, oacc[nt], 0, 0, 0);
    }
  }

  const int b = bh >> 4, h = bh & 15;
  for (int nt = 0; nt < 4; nt++)
    for (int r = 0; r < 4; r++) {
      const int qg = q0 + w * 16 + quad * 4 + r;
      const float o = oacc[nt][r] / li[r];
      AO[(size_t)(b * NS + qg) * ND + h * 64 + nt * 16 + l15] = f2bf(o);
    }
}

extern "C" void kernel_launch(void* const* d_in, const int* in_sizes, int n_in,
                              void* d_out, int out_size, void* d_ws, size_t ws_size,
                              hipStream_t stream) {
  const void* x = d_in[0];           // fp32 [B][S][D]
  const int* tp = (const int*)d_in[1];
  const void* Wq = d_in[2];          // fp32 [D][D]
  const void* Wk = d_in[3];
  const void* Wv = d_in[4];
  const void* Wo = d_in[5];

  const size_t NE = (size_t)NB * NS * ND;  // 8,388,608
  u16* Qb = (u16*)d_ws;
  u16* Kb = Qb + NE;
  u16* Vb = Kb + NE;
  u16* AO = Vb + NE;  // ws use: 4*NE*2 = 67.1 MB

  dim3 blk(256);
  // QKV projections + fused RoPE(Q,K), bf16 head-major stores
  gemm_qkv<<<dim3(64, 8, 3), blk, 0, stream>>>(x, Wq, Wk, Wv, Qb, Kb, Vb, tp, 0, 0);
  // causal MFMA flash attention -> AO (bf16, row-major)
  attn<<<dim3(NS / 64, NB * NH), blk, 0, stream>>>(Qb, Kb, Vb, AO);
  // output projection -> d_out as FP32 (reference output dtype)
  gemm_qkv<<<dim3(64, 8, 1), blk, 0, stream>>>(AO, Wo, Wo, Wo, d_out, d_out, d_out, tp, 3, 1);
}

// Round 7
// 571.316 us; speedup vs baseline: 1.7646x; 1.7646x over previous
//
#include <hip/hip_runtime.h>

typedef unsigned short u16;
typedef __bf16 bf16x8 __attribute__((ext_vector_type(8)));
typedef float f32x4 __attribute__((ext_vector_type(4)));
typedef u16 u16x8 __attribute__((ext_vector_type(8)));

union V8 { u16x8 u; bf16x8 b; };

#define NB 4
#define NS 2048
#define ND 1024
#define NH 16
#define NDK 64
#define LP 80   // padded LDS row stride for staging (u16)
#define CP 136  // padded LDS row stride for C-tile epilogue (u16)

__device__ __forceinline__ u16 f2bf(float f) {
  union { float f; unsigned u; } v; v.f = f;
  return (u16)((v.u + 0x7fffu + ((v.u >> 16) & 1u)) >> 16);  // RNE
}

__device__ __forceinline__ bf16x8 lds_frag(const u16* p) {
  V8 t; t.u = *(const u16x8*)p; return t.b;
}

// Load 8 consecutive elements (as bf16 bits); source fp32 or bf16 (wave-uniform).
__device__ __forceinline__ u16x8 load8(const void* base, size_t elem_off, int isbf) {
  u16x8 r;
  if (isbf) {
    r = *(const u16x8*)((const u16*)base + elem_off);
  } else {
    const float* f = (const float*)base + elem_off;
    const f32x4 lo = *(const f32x4*)f;
    const f32x4 hi = *(const f32x4*)(f + 4);
    for (int j = 0; j < 4; j++) { r[j] = f2bf(lo[j]); r[j + 4] = f2bf(hi[j]); }
  }
  return r;
}

// C = X @ W^T (M=8192, N=1024, K=1024), 128x128 tile, BK=64, 4 waves.
// mode 0/1: RoPE epilogue, bf16 store [B][H][S][DK] (Q, K)
// mode 2:   bf16 store [B][H][S][DK] (V)
// mode 3:   fp32 store row-major [M][N] (final output — d_out is float*)
__global__ __launch_bounds__(256) void gemm_qkv(
    const void* __restrict__ X, const void* __restrict__ W0,
    const void* __restrict__ W1, const void* __restrict__ W2,
    void* __restrict__ O0, void* __restrict__ O1, void* __restrict__ O2,
    const int* __restrict__ tokpos, int modebase, int abf) {
  __shared__ u16 smem[2 * 128 * LP];  // 40 KB: A|B staging, reused for C tile
  u16* ldsA = smem;
  u16* ldsB = smem + 128 * LP;
  const int tid = threadIdx.x;
  const int lane = tid & 63;
  const int w = tid >> 6;
  const int quad = lane >> 4;
  const int l15 = lane & 15;
  const int z = blockIdx.z;
  const void* Wp = (z == 0) ? W0 : (z == 1) ? W1 : W2;
  void* Op = (z == 0) ? O0 : (z == 1) ? O1 : O2;
  const int mode = modebase + z;
  const int m0 = blockIdx.x * 128;
  const int n0 = blockIdx.y * 128;
  const int wm = (w >> 1) * 64;
  const int wn = (w & 1) * 64;

  const int srow = tid >> 3;        // 0..31
  const int scol = (tid & 7) * 8;   // 0..56

  f32x4 acc[4][4];
  const f32x4 z4 = {0.f, 0.f, 0.f, 0.f};
  for (int i = 0; i < 4; i++)
    for (int j = 0; j < 4; j++) acc[i][j] = z4;

  for (int k0 = 0; k0 < ND; k0 += 64) {
    u16x8 ar[4], br[4];
    for (int r = 0; r < 4; r++) {
      ar[r] = load8(X, (size_t)(m0 + r * 32 + srow) * ND + k0 + scol, abf);
      br[r] = load8(Wp, (size_t)(n0 + r * 32 + srow) * ND + k0 + scol, 0);
    }
    __syncthreads();  // WAR
    for (int r = 0; r < 4; r++) {
      *(u16x8*)&ldsA[(r * 32 + srow) * LP + scol] = ar[r];
      *(u16x8*)&ldsB[(r * 32 + srow) * LP + scol] = br[r];
    }
    __syncthreads();  // RAW
    for (int kk = 0; kk < 2; kk++) {
      bf16x8 af[4], bfr[4];
      for (int mt = 0; mt < 4; mt++)
        af[mt] = lds_frag(&ldsA[(wm + mt * 16 + l15) * LP + (kk * 4 + quad) * 8]);
      for (int nt = 0; nt < 4; nt++)
        bfr[nt] = lds_frag(&ldsB[(wn + nt * 16 + l15) * LP + (kk * 4 + quad) * 8]);
      for (int mt = 0; mt < 4; mt++)
        for (int nt = 0; nt < 4; nt++)
          acc[mt][nt] = __builtin_amdgcn_mfma_f32_16x16x32_bf16(
              af[mt], bfr[nt], acc[mt][nt], 0, 0, 0);
    }
  }

  // epilogue: C(m_g, n_g): m_g = m0+wm+mt*16+quad*4+r, n_g = n0+wn+nt*16+l15
  if (mode <= 2) {
    // ---- bf16 path: RoPE (Q,K) in-register, then LDS-staged coalesced store
    __syncthreads();  // staging buffer reuse (all MFMA LDS reads done)
    u16* cb = smem;   // C tile [128][CP] u16 = 34.8 KB
    for (int nt = 0; nt < 4; nt++) {
      const int n_g = n0 + wn + nt * 16 + l15;
      const int dk = n_g & 63;
      const float sgn = (dk & 1) ? 1.f : -1.f;
      float inv_freq = 0.f;
      if (mode < 2)
        inv_freq = __expf(-(float)(dk >> 1) * 0.28782313662425572f);  // ln(1e4)/32
      for (int mt = 0; mt < 4; mt++) {
        const int mrow = wm + mt * 16 + quad * 4;
        for (int r = 0; r < 4; r++) {
          const int m_g = m0 + mrow + r;
          float v = acc[mt][nt][r];
          if (mode < 2) {
            // RoPE: pair (2i,2i+1) sits in adjacent lanes (dk on lane&15)
            const int s_i = m_g & (NS - 1);
            const float pos = (float)tokpos[s_i];
            const float partner = __shfl_xor(v, 1);
            float sn, cs;
            __sincosf(pos * inv_freq, &sn, &cs);
            v = v * cs + partner * sn * sgn;
          }
          cb[(mrow + r) * CP + wn + nt * 16 + l15] = f2bf(v);
        }
      }
    }
    __syncthreads();
    // coalesced store: 16 threads/row cover 128 u16; 8 passes over 128 rows.
    // 8-lane groups write 128 B contiguous (one head's full dk row).
    const int c = (tid & 15) * 8;        // 0..120
    const int h = (n0 + c) >> 6;
    const int dk0 = (n0 + c) & 63;
    for (int p = 0; p < 8; p++) {
      const int row = p * 16 + (tid >> 4);
      const int m_g = m0 + row;
      const int b = m_g >> 11;
      const int s_i = m_g & (NS - 1);
      *(u16x8*)&((u16*)Op)[(size_t)(((b * NH) + h) * NS + s_i) * NDK + dk0] =
          *(const u16x8*)&cb[row * CP + c];
    }
  } else {
    // ---- fp32 path (final output): quads give 64 B-contiguous chunks
    for (int nt = 0; nt < 4; nt++) {
      const int n_g = n0 + wn + nt * 16 + l15;
      for (int mt = 0; mt < 4; mt++) {
        const int mb = m0 + wm + mt * 16 + quad * 4;
        for (int r = 0; r < 4; r++)
          ((float*)Op)[(size_t)(mb + r) * ND + n_g] = acc[mt][nt][r];
      }
    }
  }
}

// causal flash attention: 1 block = 64 queries (16/wave), 64-key tiles.
// V transposed into LDS at staging; AO written bf16 row-major [B*S][D]
// via LDS-staged coalesced 16 B stores.
__global__ __launch_bounds__(256) void attn(const u16* __restrict__ Q,
                                            const u16* __restrict__ Kc,
                                            const u16* __restrict__ Vv,
                                            u16* __restrict__ AO) {
  __shared__ u16 kt[64 * LP];        // [key][dk]; reused for O tile at end
  __shared__ u16 vt[64 * LP];        // [dk][key]
  __shared__ u16 pbuf[4][16 * LP];   // per-wave P: [query][key]
  const int tid = threadIdx.x;
  const int lane = tid & 63;
  const int w = tid >> 6;
  const int quad = lane >> 4;
  const int l15 = lane & 15;
  const int bh = blockIdx.y;
  const int q0 = (gridDim.x - 1 - blockIdx.x) * 64;  // heavy diagonal first

  // Q fragments resident: A[m=lane&15 (query)][k=quad*8+j (dk)]
  const u16* Qb = Q + (size_t)bh * NS * NDK + (size_t)(q0 + w * 16 + l15) * NDK + quad * 8;
  const bf16x8 qf0 = lds_frag(Qb);
  const bf16x8 qf1 = lds_frag(Qb + 32);

  f32x4 oacc[4];
  const f32x4 z4 = {0.f, 0.f, 0.f, 0.f};
  for (int i = 0; i < 4; i++) oacc[i] = z4;
  float mi[4], li[4];
  for (int r = 0; r < 4; r++) { mi[r] = -1e30f; li[r] = 0.f; }

  const int srow = tid >> 3;        // 0..31
  const int scol = (tid & 7) * 8;   // 0..56
  const u16* Kb = Kc + (size_t)bh * NS * NDK;
  const u16* Vb = Vv + (size_t)bh * NS * NDK;
  u16* pw = pbuf[w];

  for (int j0 = 0; j0 <= q0; j0 += 64) {
    u16x8 kreg[2], vreg[2];
    for (int r = 0; r < 2; r++) {
      kreg[r] = *(const u16x8*)(Kb + (size_t)(j0 + r * 32 + srow) * NDK + scol);
      vreg[r] = *(const u16x8*)(Vb + (size_t)(j0 + r * 32 + srow) * NDK + scol);
    }
    __syncthreads();  // WAR
    for (int r = 0; r < 2; r++) {
      *(u16x8*)&kt[(r * 32 + srow) * LP + scol] = kreg[r];
      for (int j = 0; j < 8; j++)                      // transpose V: [dk][key]
        vt[(scol + j) * LP + r * 32 + srow] = vreg[r][j];
    }
    __syncthreads();  // RAW

    // S = Q K^T : D[row=query(quad*4+r)][col=key(l15)] per 16-key tile nt
    f32x4 sa[4];
    for (int i = 0; i < 4; i++) sa[i] = z4;
    for (int kk = 0; kk < 2; kk++) {
      const bf16x8 qf = kk ? qf1 : qf0;
      for (int nt = 0; nt < 4; nt++) {
        const bf16x8 kf = lds_frag(&kt[(nt * 16 + l15) * LP + (kk * 4 + quad) * 8]);
        sa[nt] = __builtin_amdgcn_mfma_f32_16x16x32_bf16(qf, kf, sa[nt], 0, 0, 0);
      }
    }

    const bool diag = (j0 == q0);
    float pv[4][4];
    float rm[4] = {-3e30f, -3e30f, -3e30f, -3e30f};
    for (int nt = 0; nt < 4; nt++) {
      const int kg = j0 + nt * 16 + l15;
      for (int r = 0; r < 4; r++) {
        float s = sa[nt][r] * 0.125f;  // 1/sqrt(64)
        if (diag) {
          const int qg = q0 + w * 16 + quad * 4 + r;
          if (kg > qg) s = -1e30f;
        }
        pv[nt][r] = s;
        rm[r] = fmaxf(rm[r], s);
      }
    }
    for (int r = 0; r < 4; r++) {
      for (int m = 1; m < 16; m <<= 1) rm[r] = fmaxf(rm[r], __shfl_xor(rm[r], m));
      const float mnew = fmaxf(mi[r], rm[r]);
      const float alpha = __expf(mi[r] - mnew);
      mi[r] = mnew;
      li[r] *= alpha;
      for (int nt = 0; nt < 4; nt++) oacc[nt][r] *= alpha;
    }
    float rs[4] = {0.f, 0.f, 0.f, 0.f};
    for (int nt = 0; nt < 4; nt++)
      for (int r = 0; r < 4; r++) {
        const float p = __expf(pv[nt][r] - mi[r]);
        pv[nt][r] = p;
        rs[r] += p;
      }
    for (int r = 0; r < 4; r++) {
      for (int m = 1; m < 16; m <<= 1) rs[r] += __shfl_xor(rs[r], m);
      li[r] += rs[r];
    }

    // P: C-layout -> A-layout via per-wave LDS, ordered by a full barrier
    for (int nt = 0; nt < 4; nt++)
      for (int r = 0; r < 4; r++)
        pw[(quad * 4 + r) * LP + nt * 16 + l15] = f2bf(pv[nt][r]);
    __syncthreads();
    const bf16x8 pf0 = lds_frag(&pw[l15 * LP + quad * 8]);
    const bf16x8 pf1 = lds_frag(&pw[l15 * LP + 32 + quad * 8]);

    // O += P V : B[n=dk (l15)][k=key (quad*8+j)] from transposed vt rows
    for (int nt = 0; nt < 4; nt++) {
      const int rv = nt * 16 + l15;
      const bf16x8 vf0 = lds_frag(&vt[rv * LP + quad * 8]);
      const bf16x8 vf1 = lds_frag(&vt[rv * LP + 32 + quad * 8]);
      oacc[nt] = __builtin_amdgcn_mfma_f32_16x16x32_bf16(pf0, vf0, oacc[nt], 0, 0, 0);
      oacc[nt] = __builtin_amdgcn_mfma_f32_16x16x32_bf16(pf1, vf1, oacc[nt], 0, 0, 0);
    }
  }

  // epilogue: stage O tile [64][72] in kt, then coalesced 16 B stores
  __syncthreads();  // kt reuse (all MFMA LDS reads done)
  u16* ob = kt;     // stride 72 u16 (144 B, 16 B-aligned)
  for (int nt = 0; nt < 4; nt++)
    for (int r = 0; r < 4; r++)
      ob[(w * 16 + quad * 4 + r) * 72 + nt * 16 + l15] = f2bf(oacc[nt][r] / li[r]);
  __syncthreads();
  const int b = bh >> 4, h = bh & 15;
  for (int p = 0; p < 2; p++) {
    const int idx = p * 256 + tid;
    const int row = idx >> 3;          // query row 0..63
    const int c = (idx & 7) * 8;       // dk chunk
    const int qg = q0 + row;
    *(u16x8*)&AO[(size_t)(b * NS + qg) * ND + h * 64 + c] =
        *(const u16x8*)&ob[row * 72 + c];
  }
}

extern "C" void kernel_launch(void* const* d_in, const int* in_sizes, int n_in,
                              void* d_out, int out_size, void* d_ws, size_t ws_size,
                              hipStream_t stream) {
  const void* x = d_in[0];           // fp32 [B][S][D]
  const int* tp = (const int*)d_in[1];
  const void* Wq = d_in[2];          // fp32 [D][D]
  const void* Wk = d_in[3];
  const void* Wv = d_in[4];
  const void* Wo = d_in[5];

  const size_t NE = (size_t)NB * NS * ND;  // 8,388,608
  u16* Qb = (u16*)d_ws;
  u16* Kb = Qb + NE;
  u16* Vb = Kb + NE;
  u16* AO = Vb + NE;  // ws use: 4*NE*2 = 67.1 MB

  dim3 blk(256);
  // QKV projections + fused RoPE(Q,K), bf16 head-major stores
  gemm_qkv<<<dim3(64, 8, 3), blk, 0, stream>>>(x, Wq, Wk, Wv, Qb, Kb, Vb, tp, 0, 0);
  // causal MFMA flash attention -> AO (bf16, row-major)
  attn<<<dim3(NS / 64, NB * NH), blk, 0, stream>>>(Qb, Kb, Vb, AO);
  // output projection -> d_out as FP32 (reference output dtype)
  gemm_qkv<<<dim3(64, 8, 1), blk, 0, stream>>>(AO, Wo, Wo, Wo, d_out, d_out, d_out, tp, 3, 1);
}

// Round 8
// 436.472 us; speedup vs baseline: 2.3098x; 1.3089x over previous
//
#include <hip/hip_runtime.h>

typedef unsigned short u16;
typedef __bf16 bf16x8 __attribute__((ext_vector_type(8)));
typedef float f32x4 __attribute__((ext_vector_type(4)));
typedef u16 u16x8 __attribute__((ext_vector_type(8)));
typedef u16 u16x4 __attribute__((ext_vector_type(4)));
typedef short s16x4 __attribute__((ext_vector_type(4)));

union V8 { u16x8 u; bf16x8 b; };
union V4 { u16x4 u; s16x4 s; };

#define NB 4
#define NS 2048
#define ND 1024
#define NH 16
#define NDK 64
#define LP 80   // padded LDS row stride for staging (u16)
#define CP 136  // padded LDS row stride for C-tile epilogue (u16)

__device__ __forceinline__ u16 f2bf(float f) {
  union { float f; unsigned u; } v; v.f = f;
  return (u16)((v.u + 0x7fffu + ((v.u >> 16) & 1u)) >> 16);  // RNE
}

__device__ __forceinline__ bf16x8 lds_frag(const u16* p) {
  V8 t; t.u = *(const u16x8*)p; return t.b;
}

// Load 8 consecutive elements (as bf16 bits); source fp32 or bf16 (wave-uniform).
__device__ __forceinline__ u16x8 load8(const void* base, size_t elem_off, int isbf) {
  u16x8 r;
  if (isbf) {
    r = *(const u16x8*)((const u16*)base + elem_off);
  } else {
    const float* f = (const float*)base + elem_off;
    const f32x4 lo = *(const f32x4*)f;
    const f32x4 hi = *(const f32x4*)(f + 4);
    for (int j = 0; j < 4; j++) { r[j] = f2bf(lo[j]); r[j + 4] = f2bf(hi[j]); }
  }
  return r;
}

// ==================== GEMM (unchanged from round 7) ====================
__global__ __launch_bounds__(256) void gemm_qkv(
    const void* __restrict__ X, const void* __restrict__ W0,
    const void* __restrict__ W1, const void* __restrict__ W2,
    void* __restrict__ O0, void* __restrict__ O1, void* __restrict__ O2,
    const int* __restrict__ tokpos, int modebase, int abf) {
  __shared__ u16 smem[2 * 128 * LP];  // 40 KB: A|B staging, reused for C tile
  u16* ldsA = smem;
  u16* ldsB = smem + 128 * LP;
  const int tid = threadIdx.x;
  const int lane = tid & 63;
  const int w = tid >> 6;
  const int quad = lane >> 4;
  const int l15 = lane & 15;
  const int z = blockIdx.z;
  const void* Wp = (z == 0) ? W0 : (z == 1) ? W1 : W2;
  void* Op = (z == 0) ? O0 : (z == 1) ? O1 : O2;
  const int mode = modebase + z;
  const int m0 = blockIdx.x * 128;
  const int n0 = blockIdx.y * 128;
  const int wm = (w >> 1) * 64;
  const int wn = (w & 1) * 64;

  const int srow = tid >> 3;        // 0..31
  const int scol = (tid & 7) * 8;   // 0..56

  f32x4 acc[4][4];
  const f32x4 z4 = {0.f, 0.f, 0.f, 0.f};
  for (int i = 0; i < 4; i++)
    for (int j = 0; j < 4; j++) acc[i][j] = z4;

  for (int k0 = 0; k0 < ND; k0 += 64) {
    u16x8 ar[4], br[4];
    for (int r = 0; r < 4; r++) {
      ar[r] = load8(X, (size_t)(m0 + r * 32 + srow) * ND + k0 + scol, abf);
      br[r] = load8(Wp, (size_t)(n0 + r * 32 + srow) * ND + k0 + scol, 0);
    }
    __syncthreads();  // WAR
    for (int r = 0; r < 4; r++) {
      *(u16x8*)&ldsA[(r * 32 + srow) * LP + scol] = ar[r];
      *(u16x8*)&ldsB[(r * 32 + srow) * LP + scol] = br[r];
    }
    __syncthreads();  // RAW
    for (int kk = 0; kk < 2; kk++) {
      bf16x8 af[4], bfr[4];
      for (int mt = 0; mt < 4; mt++)
        af[mt] = lds_frag(&ldsA[(wm + mt * 16 + l15) * LP + (kk * 4 + quad) * 8]);
      for (int nt = 0; nt < 4; nt++)
        bfr[nt] = lds_frag(&ldsB[(wn + nt * 16 + l15) * LP + (kk * 4 + quad) * 8]);
      for (int mt = 0; mt < 4; mt++)
        for (int nt = 0; nt < 4; nt++)
          acc[mt][nt] = __builtin_amdgcn_mfma_f32_16x16x32_bf16(
              af[mt], bfr[nt], acc[mt][nt], 0, 0, 0);
    }
  }

  if (mode <= 2) {
    __syncthreads();
    u16* cb = smem;   // C tile [128][CP]
    for (int nt = 0; nt < 4; nt++) {
      const int n_g = n0 + wn + nt * 16 + l15;
      const int dk = n_g & 63;
      const float sgn = (dk & 1) ? 1.f : -1.f;
      float inv_freq = 0.f;
      if (mode < 2)
        inv_freq = __expf(-(float)(dk >> 1) * 0.28782313662425572f);  // ln(1e4)/32
      for (int mt = 0; mt < 4; mt++) {
        const int mrow = wm + mt * 16 + quad * 4;
        for (int r = 0; r < 4; r++) {
          const int m_g = m0 + mrow + r;
          float v = acc[mt][nt][r];
          if (mode < 2) {
            const int s_i = m_g & (NS - 1);
            const float pos = (float)tokpos[s_i];
            const float partner = __shfl_xor(v, 1);
            float sn, cs;
            __sincosf(pos * inv_freq, &sn, &cs);
            v = v * cs + partner * sn * sgn;
          }
          cb[(mrow + r) * CP + wn + nt * 16 + l15] = f2bf(v);
        }
      }
    }
    __syncthreads();
    const int c = (tid & 15) * 8;
    const int h = (n0 + c) >> 6;
    const int dk0 = (n0 + c) & 63;
    for (int p = 0; p < 8; p++) {
      const int row = p * 16 + (tid >> 4);
      const int m_g = m0 + row;
      const int b = m_g >> 11;
      const int s_i = m_g & (NS - 1);
      *(u16x8*)&((u16*)Op)[(size_t)(((b * NH) + h) * NS + s_i) * NDK + dk0] =
          *(const u16x8*)&cb[row * CP + c];
    }
  } else {
    for (int nt = 0; nt < 4; nt++) {
      const int n_g = n0 + wn + nt * 16 + l15;
      for (int mt = 0; mt < 4; mt++) {
        const int mb = m0 + wm + mt * 16 + quad * 4;
        for (int r = 0; r < 4; r++)
          ((float*)Op)[(size_t)(mb + r) * ND + n_g] = acc[mt][nt][r];
      }
    }
  }
}

// ==================== attention (S^T restructure) ====================
// 1 block = 64 queries (16/wave), 64-key tiles.
// S^T = MFMA(K,Q): C-layout row = key (quad*4+r), col = query (l15).
// Softmax state per-lane (query = l15), 2 shuffles per reduction.
// P stays in registers: S^T C-layout == A-operand layout of 16x16x16 MFMA.
// kt/vt use XOR chunk swizzle -> conflict-free staging writes.
__global__ __launch_bounds__(256) void attn(const u16* __restrict__ Q,
                                            const u16* __restrict__ Kc,
                                            const u16* __restrict__ Vv,
                                            u16* __restrict__ AO) {
  __shared__ u16 kt[64 * LP];        // [key][dk], chunk^=(key&7); reused for O
  __shared__ u16 vt[64 * LP];        // [dk][key], chunk^=((dk>>3)&7)
  const int tid = threadIdx.x;
  const int lane = tid & 63;
  const int w = tid >> 6;
  const int quad = lane >> 4;
  const int l15 = lane & 15;
  const int bh = blockIdx.y;
  const int q0 = (gridDim.x - 1 - blockIdx.x) * 64;  // heavy diagonal first
  const int qg = q0 + w * 16 + l15;                  // this lane's query

  // Q fragments: B-operand layout B[n=query l15][k=dk quad*8+j]
  const u16* Qb = Q + (size_t)bh * NS * NDK + (size_t)qg * NDK + quad * 8;
  const bf16x8 qf0 = lds_frag(Qb);
  const bf16x8 qf1 = lds_frag(Qb + 32);

  f32x4 oacc[4];  // [dk-tile]; C-layout row=query(quad*4+r), col=dk(l15)
  const f32x4 z4 = {0.f, 0.f, 0.f, 0.f};
  for (int i = 0; i < 4; i++) oacc[i] = z4;
  float mi = -1e30f, li = 0.f;  // per-lane: query = l15 (replicated over quads)

  const int srow = tid >> 3;        // 0..31
  const int sg = tid & 7;           // staging chunk 0..7
  const u16* Kb = Kc + (size_t)bh * NS * NDK;
  const u16* Vb = Vv + (size_t)bh * NS * NDK;

  for (int j0 = 0; j0 <= q0; j0 += 64) {
    u16x8 kreg[2], vreg[2];
    for (int r = 0; r < 2; r++) {
      kreg[r] = *(const u16x8*)(Kb + (size_t)(j0 + r * 32 + srow) * NDK + sg * 8);
      vreg[r] = *(const u16x8*)(Vb + (size_t)(j0 + r * 32 + srow) * NDK + sg * 8);
    }
    __syncthreads();  // WAR
    for (int r = 0; r < 2; r++) {
      const int key = r * 32 + srow;
      // kt: row=key, chunk sg swizzled by key&7 -> conflict-free write
      *(u16x8*)&kt[key * LP + (sg ^ (key & 7)) * 8] = kreg[r];
      // vt: row=dk=sg*8+j, chunk=key>>3 swizzled by (dk>>3)&7
      for (int j = 0; j < 8; j++) {
        const int dk = sg * 8 + j;
        vt[dk * LP + ((key >> 3) ^ ((dk >> 3) & 7)) * 8 + (key & 7)] = vreg[r][j];
      }
    }
    __syncthreads();  // RAW

    // S^T = K Q^T : D[row=key(quad*4+r)][col=query(l15)] per 16-key tile nt
    f32x4 sa[4];
    for (int i = 0; i < 4; i++) sa[i] = z4;
    for (int kk = 0; kk < 2; kk++) {
      const bf16x8 qf = kk ? qf1 : qf0;
      for (int nt = 0; nt < 4; nt++) {
        const int row = nt * 16 + l15;  // key
        const bf16x8 kf =
            lds_frag(&kt[row * LP + ((kk * 4 + quad) ^ (row & 7)) * 8]);
        sa[nt] = __builtin_amdgcn_mfma_f32_16x16x32_bf16(kf, qf, sa[nt], 0, 0, 0);
      }
    }

    // masked scores + per-query (lane) online softmax
    const bool diag = (j0 == q0);
    float s[4][4];
    float lmax = -3e30f;
    for (int nt = 0; nt < 4; nt++)
      for (int r = 0; r < 4; r++) {
        float v = sa[nt][r] * 0.125f;  // 1/sqrt(64)
        if (diag && (j0 + nt * 16 + quad * 4 + r) > qg) v = -1e30f;
        s[nt][r] = v;
        lmax = fmaxf(lmax, v);
      }
    lmax = fmaxf(lmax, __shfl_xor(lmax, 16));
    lmax = fmaxf(lmax, __shfl_xor(lmax, 32));
    const float mnew = fmaxf(mi, lmax);
    const float alpha = __expf(mi - mnew);
    float ps = 0.f;
    float p[4][4];
    for (int nt = 0; nt < 4; nt++)
      for (int r = 0; r < 4; r++) {
        const float e = __expf(s[nt][r] - mnew);
        p[nt][r] = e;
        ps += e;
      }
    ps += __shfl_xor(ps, 16);
    ps += __shfl_xor(ps, 32);
    li = li * alpha + ps;
    mi = mnew;

    // rescale O by alpha of its row-query (quad*4+r)
    float aq[4];
    for (int r = 0; r < 4; r++) aq[r] = __shfl(alpha, quad * 4 + r);
    for (int dt = 0; dt < 4; dt++)
      for (int r = 0; r < 4; r++) oacc[dt][r] *= aq[r];

    // P -> A-frags in-register (A[m=query l15][k=key quad*4+j] == p[nt][j])
    s16x4 pa[4];
    for (int nt = 0; nt < 4; nt++) {
      V4 t;
      for (int r = 0; r < 4; r++) t.u[r] = f2bf(p[nt][r]);
      pa[nt] = t.s;
    }

    // O += P V : B[n=dk l15][k=key quad*4+j] from swizzled vt, K=16 MFMA
    for (int dt = 0; dt < 4; dt++) {
      const int dk = dt * 16 + l15;
      const int xr = (dk >> 3) & 7;
      for (int nt = 0; nt < 4; nt++) {
        const int chunk = 2 * nt + (quad >> 1);
        V4 t;
        t.u = *(const u16x4*)&vt[dk * LP + (chunk ^ xr) * 8 + 4 * (quad & 1)];
        oacc[dt] = __builtin_amdgcn_mfma_f32_16x16x16bf16_1k(pa[nt], t.s,
                                                             oacc[dt], 0, 0, 0);
      }
    }
  }

  // epilogue: stage O tile [64][72] in kt, then coalesced 16 B stores
  __syncthreads();
  float lq[4];
  for (int r = 0; r < 4; r++) lq[r] = __shfl(li, quad * 4 + r);
  u16* ob = kt;
  for (int dt = 0; dt < 4; dt++)
    for (int r = 0; r < 4; r++)
      ob[(w * 16 + quad * 4 + r) * 72 + dt * 16 + l15] =
          f2bf(oacc[dt][r] / lq[r]);
  __syncthreads();
  const int b = bh >> 4, h = bh & 15;
  for (int p2 = 0; p2 < 2; p2++) {
    const int idx = p2 * 256 + tid;
    const int row = idx >> 3;
    const int c = (idx & 7) * 8;
    *(u16x8*)&AO[(size_t)(b * NS + q0 + row) * ND + h * 64 + c] =
        *(const u16x8*)&ob[row * 72 + c];
  }
}

extern "C" void kernel_launch(void* const* d_in, const int* in_sizes, int n_in,
                              void* d_out, int out_size, void* d_ws, size_t ws_size,
                              hipStream_t stream) {
  const void* x = d_in[0];           // fp32 [B][S][D]
  const int* tp = (const int*)d_in[1];
  const void* Wq = d_in[2];          // fp32 [D][D]
  const void* Wk = d_in[3];
  const void* Wv = d_in[4];
  const void* Wo = d_in[5];

  const size_t NE = (size_t)NB * NS * ND;  // 8,388,608
  u16* Qb = (u16*)d_ws;
  u16* Kb = Qb + NE;
  u16* Vb = Kb + NE;
  u16* AO = Vb + NE;  // ws use: 4*NE*2 = 67.1 MB

  dim3 blk(256);
  gemm_qkv<<<dim3(64, 8, 3), blk, 0, stream>>>(x, Wq, Wk, Wv, Qb, Kb, Vb, tp, 0, 0);
  attn<<<dim3(NS / 64, NB * NH), blk, 0, stream>>>(Qb, Kb, Vb, AO);
  gemm_qkv<<<dim3(64, 8, 1), blk, 0, stream>>>(AO, Wo, Wo, Wo, d_out, d_out, d_out, tp, 3, 1);
}

// Round 9
// 364.490 us; speedup vs baseline: 2.7659x; 1.1975x over previous
//
#include <hip/hip_runtime.h>

typedef unsigned short u16;
typedef __bf16 bf16x8 __attribute__((ext_vector_type(8)));
typedef float f32x4 __attribute__((ext_vector_type(4)));
typedef u16 u16x8 __attribute__((ext_vector_type(8)));
typedef u16 u16x4 __attribute__((ext_vector_type(4)));
typedef short s16x4 __attribute__((ext_vector_type(4)));

union V8 { u16x8 u; bf16x8 b; };
union V4 { u16x4 u; s16x4 s; unsigned w[2]; };

#define NB 4
#define NS 2048
#define ND 1024
#define NH 16
#define NDK 64
#define LP 80   // padded LDS row stride for staging (u16)
#define CP 136  // padded LDS row stride for C-tile epilogue (u16)
// softmax scale folded into Q: 1/sqrt(64) * log2(e) -> scores in exp2 domain
#define QSCL 0.18033688011112042f

__device__ __forceinline__ u16 f2bf(float f) {
  union { float f; unsigned u; } v; v.f = f;
  return (u16)((v.u + 0x7fffu + ((v.u >> 16) & 1u)) >> 16);  // RNE
}

// pack two fp32 -> two bf16 (low = a, high = b)
__device__ __forceinline__ unsigned pk2bf(float a, float b) {
#if __has_builtin(__builtin_amdgcn_cvt_pk_bf16_f32)
  auto v = __builtin_amdgcn_cvt_pk_bf16_f32(a, b);
  unsigned r; __builtin_memcpy(&r, &v, 4);
  return r;
#else
  return (unsigned)f2bf(a) | ((unsigned)f2bf(b) << 16);
#endif
}

__device__ __forceinline__ float fexp2(float x) {
#if __has_builtin(__builtin_amdgcn_exp2f)
  return __builtin_amdgcn_exp2f(x);
#else
  return exp2f(x);
#endif
}

__device__ __forceinline__ bf16x8 lds_frag(const u16* p) {
  V8 t; t.u = *(const u16x8*)p; return t.b;
}

// one-time fp32 -> bf16 conversion (memory-bound)
__global__ __launch_bounds__(256) void cvt_bf16(const float* __restrict__ s,
                                                u16* __restrict__ d, int n) {
  const int i = (blockIdx.x * 256 + threadIdx.x) * 8;
  if (i >= n) return;
  const f32x4 lo = *(const f32x4*)(s + i);
  const f32x4 hi = *(const f32x4*)(s + i + 4);
  union { unsigned w[4]; u16x8 v; } o;
  o.w[0] = pk2bf(lo[0], lo[1]);
  o.w[1] = pk2bf(lo[2], lo[3]);
  o.w[2] = pk2bf(hi[0], hi[1]);
  o.w[3] = pk2bf(hi[2], hi[3]);
  *(u16x8*)(d + i) = o.v;
}

// ==================== GEMM (all-bf16 operands) ====================
// C = X @ W^T (M=8192, N=1024, K=1024), 128x128 tile, BK=64, 4 waves.
// mode 0: RoPE + QSCL, bf16 [B][H][S][DK];  mode 1: RoPE, bf16 head-major;
// mode 2: bf16 head-major;  mode 3: fp32 row-major [M][N] (final output).
__global__ __launch_bounds__(256) void gemm_qkv(
    const u16* __restrict__ X, const u16* __restrict__ W0,
    const u16* __restrict__ W1, const u16* __restrict__ W2,
    void* __restrict__ O0, void* __restrict__ O1, void* __restrict__ O2,
    const int* __restrict__ tokpos, int modebase) {
  __shared__ u16 smem[2 * 128 * LP];  // 40 KB: A|B staging, reused for C tile
  u16* ldsA = smem;
  u16* ldsB = smem + 128 * LP;
  const int tid = threadIdx.x;
  const int lane = tid & 63;
  const int w = tid >> 6;
  const int quad = lane >> 4;
  const int l15 = lane & 15;
  const int z = blockIdx.z;
  const u16* Wp = (z == 0) ? W0 : (z == 1) ? W1 : W2;
  void* Op = (z == 0) ? O0 : (z == 1) ? O1 : O2;
  const int mode = modebase + z;
  const int m0 = blockIdx.x * 128;
  const int n0 = blockIdx.y * 128;
  const int wm = (w >> 1) * 64;
  const int wn = (w & 1) * 64;

  const int srow = tid >> 3;        // 0..31
  const int scol = (tid & 7) * 8;   // 0..56
  const u16* Ag = X + (size_t)(m0 + srow) * ND + scol;
  const u16* Bg = Wp + (size_t)(n0 + srow) * ND + scol;

  f32x4 acc[4][4];
  const f32x4 z4 = {0.f, 0.f, 0.f, 0.f};
  for (int i = 0; i < 4; i++)
    for (int j = 0; j < 4; j++) acc[i][j] = z4;

  for (int k0 = 0; k0 < ND; k0 += 64) {
    u16x8 ar[4], br[4];
    for (int r = 0; r < 4; r++) {
      ar[r] = *(const u16x8*)(Ag + (size_t)r * 32 * ND + k0);
      br[r] = *(const u16x8*)(Bg + (size_t)r * 32 * ND + k0);
    }
    __syncthreads();  // WAR
    for (int r = 0; r < 4; r++) {
      *(u16x8*)&ldsA[(r * 32 + srow) * LP + scol] = ar[r];
      *(u16x8*)&ldsB[(r * 32 + srow) * LP + scol] = br[r];
    }
    __syncthreads();  // RAW
    for (int kk = 0; kk < 2; kk++) {
      bf16x8 af[4], bfr[4];
      for (int mt = 0; mt < 4; mt++)
        af[mt] = lds_frag(&ldsA[(wm + mt * 16 + l15) * LP + (kk * 4 + quad) * 8]);
      for (int nt = 0; nt < 4; nt++)
        bfr[nt] = lds_frag(&ldsB[(wn + nt * 16 + l15) * LP + (kk * 4 + quad) * 8]);
      for (int mt = 0; mt < 4; mt++)
        for (int nt = 0; nt < 4; nt++)
          acc[mt][nt] = __builtin_amdgcn_mfma_f32_16x16x32_bf16(
              af[mt], bfr[nt], acc[mt][nt], 0, 0, 0);
    }
  }

  if (mode <= 2) {
    __syncthreads();
    u16* cb = smem;   // C tile [128][CP]
    for (int nt = 0; nt < 4; nt++) {
      const int n_g = n0 + wn + nt * 16 + l15;
      const int dk = n_g & 63;
      const float sgn = (dk & 1) ? 1.f : -1.f;
      float inv_freq = 0.f;
      if (mode < 2)
        inv_freq = __expf(-(float)(dk >> 1) * 0.28782313662425572f);  // ln(1e4)/32
      for (int mt = 0; mt < 4; mt++) {
        const int mrow = wm + mt * 16 + quad * 4;
        for (int r = 0; r < 4; r++) {
          const int m_g = m0 + mrow + r;
          float v = acc[mt][nt][r];
          if (mode < 2) {
            const int s_i = m_g & (NS - 1);
            const float pos = (float)tokpos[s_i];
            const float partner = __shfl_xor(v, 1);
            float sn, cs;
            __sincosf(pos * inv_freq, &sn, &cs);
            v = v * cs + partner * sn * sgn;
            if (mode == 0) v *= QSCL;  // fold softmax scale+log2e into Q
          }
          cb[(mrow + r) * CP + wn + nt * 16 + l15] = f2bf(v);
        }
      }
    }
    __syncthreads();
    const int c = (tid & 15) * 8;
    const int h = (n0 + c) >> 6;
    const int dk0 = (n0 + c) & 63;
    for (int p = 0; p < 8; p++) {
      const int row = p * 16 + (tid >> 4);
      const int m_g = m0 + row;
      const int b = m_g >> 11;
      const int s_i = m_g & (NS - 1);
      *(u16x8*)&((u16*)Op)[(size_t)(((b * NH) + h) * NS + s_i) * NDK + dk0] =
          *(const u16x8*)&cb[row * CP + c];
    }
  } else {
    for (int nt = 0; nt < 4; nt++) {
      const int n_g = n0 + wn + nt * 16 + l15;
      for (int mt = 0; mt < 4; mt++) {
        const int mb = m0 + wm + mt * 16 + quad * 4;
        for (int r = 0; r < 4; r++)
          ((float*)Op)[(size_t)(mb + r) * ND + n_g] = acc[mt][nt][r];
      }
    }
  }
}

// ==================== attention (S^T, exp2-domain softmax) ====================
__global__ __launch_bounds__(256) void attn(const u16* __restrict__ Q,
                                            const u16* __restrict__ Kc,
                                            const u16* __restrict__ Vv,
                                            u16* __restrict__ AO) {
  __shared__ u16 kt[64 * LP];        // [key][dk], chunk^=(key&7); reused for O
  __shared__ u16 vt[64 * LP];        // [dk][key], chunk^=((dk>>3)&7)
  const int tid = threadIdx.x;
  const int lane = tid & 63;
  const int w = tid >> 6;
  const int quad = lane >> 4;
  const int l15 = lane & 15;
  const int bh = blockIdx.y;
  const int q0 = (gridDim.x - 1 - blockIdx.x) * 64;  // heavy diagonal first
  const int qg = q0 + w * 16 + l15;                  // this lane's query

  // Q fragments: B-operand layout B[n=query l15][k=dk quad*8+j]
  const u16* Qb = Q + (size_t)bh * NS * NDK + (size_t)qg * NDK + quad * 8;
  const bf16x8 qf0 = lds_frag(Qb);
  const bf16x8 qf1 = lds_frag(Qb + 32);

  f32x4 oacc[4];  // [dk-tile]; C-layout row=query(quad*4+r), col=dk(l15)
  const f32x4 z4 = {0.f, 0.f, 0.f, 0.f};
  for (int i = 0; i < 4; i++) oacc[i] = z4;
  float mi = -1e30f, li = 0.f;  // per-lane: query = l15 (replicated over quads)

  const int srow = tid >> 3;        // 0..31
  const int sg = tid & 7;           // staging chunk 0..7
  const u16* Kb = Kc + (size_t)bh * NS * NDK;
  const u16* Vb = Vv + (size_t)bh * NS * NDK;

  for (int j0 = 0; j0 <= q0; j0 += 64) {
    u16x8 kreg[2], vreg[2];
    for (int r = 0; r < 2; r++) {
      kreg[r] = *(const u16x8*)(Kb + (size_t)(j0 + r * 32 + srow) * NDK + sg * 8);
      vreg[r] = *(const u16x8*)(Vb + (size_t)(j0 + r * 32 + srow) * NDK + sg * 8);
    }
    __syncthreads();  // WAR
    for (int r = 0; r < 2; r++) {
      const int key = r * 32 + srow;
      *(u16x8*)&kt[key * LP + (sg ^ (key & 7)) * 8] = kreg[r];
      for (int j = 0; j < 8; j++) {
        const int dk = sg * 8 + j;
        vt[dk * LP + ((key >> 3) ^ ((dk >> 3) & 7)) * 8 + (key & 7)] = vreg[r][j];
      }
    }
    __syncthreads();  // RAW

    // S^T = K Q^T : D[row=key(quad*4+r)][col=query(l15)] per 16-key tile nt
    f32x4 sa[4];
    for (int i = 0; i < 4; i++) sa[i] = z4;
    for (int kk = 0; kk < 2; kk++) {
      const bf16x8 qf = kk ? qf1 : qf0;
      for (int nt = 0; nt < 4; nt++) {
        const int row = nt * 16 + l15;  // key
        const bf16x8 kf =
            lds_frag(&kt[row * LP + ((kk * 4 + quad) ^ (row & 7)) * 8]);
        sa[nt] = __builtin_amdgcn_mfma_f32_16x16x32_bf16(kf, qf, sa[nt], 0, 0, 0);
      }
    }

    // scores are already in exp2 domain (scale folded into Q)
    const bool diag = (j0 == q0);
    float s[4][4];
    float lmax = -3e30f;
    for (int nt = 0; nt < 4; nt++)
      for (int r = 0; r < 4; r++) {
        float v = sa[nt][r];
        if (diag && (j0 + nt * 16 + quad * 4 + r) > qg) v = -1e30f;
        s[nt][r] = v;
        lmax = fmaxf(lmax, v);
      }
    lmax = fmaxf(lmax, __shfl_xor(lmax, 16));
    lmax = fmaxf(lmax, __shfl_xor(lmax, 32));
    const float mnew = fmaxf(mi, lmax);
    const float alpha = fexp2(mi - mnew);
    float ps = 0.f;
    float p[4][4];
    for (int nt = 0; nt < 4; nt++)
      for (int r = 0; r < 4; r++) {
        const float e = fexp2(s[nt][r] - mnew);
        p[nt][r] = e;
        ps += e;
      }
    ps += __shfl_xor(ps, 16);
    ps += __shfl_xor(ps, 32);
    li = li * alpha + ps;
    mi = mnew;

    // rescale O by alpha of its row-query (quad*4+r)
    float aq[4];
    for (int r = 0; r < 4; r++) aq[r] = __shfl(alpha, quad * 4 + r);
    for (int dt = 0; dt < 4; dt++)
      for (int r = 0; r < 4; r++) oacc[dt][r] *= aq[r];

    // P -> A-frags in-register (A[m=query l15][k=key quad*4+j] == p[nt][j])
    s16x4 pa[4];
    for (int nt = 0; nt < 4; nt++) {
      V4 t;
      t.w[0] = pk2bf(p[nt][0], p[nt][1]);
      t.w[1] = pk2bf(p[nt][2], p[nt][3]);
      pa[nt] = t.s;
    }

    // O += P V : B[n=dk l15][k=key quad*4+j] from swizzled vt, K=16 MFMA
    for (int dt = 0; dt < 4; dt++) {
      const int dk = dt * 16 + l15;
      const int xr = (dk >> 3) & 7;
      for (int nt = 0; nt < 4; nt++) {
        const int chunk = 2 * nt + (quad >> 1);
        V4 t;
        t.u = *(const u16x4*)&vt[dk * LP + (chunk ^ xr) * 8 + 4 * (quad & 1)];
        oacc[dt] = __builtin_amdgcn_mfma_f32_16x16x16bf16_1k(pa[nt], t.s,
                                                             oacc[dt], 0, 0, 0);
      }
    }
  }

  // epilogue: stage O tile [64][72] in kt, then coalesced 16 B stores
  __syncthreads();
  float lq[4];
  for (int r = 0; r < 4; r++) lq[r] = __shfl(li, quad * 4 + r);
  u16* ob = kt;
  for (int dt = 0; dt < 4; dt++)
    for (int r = 0; r < 4; r++)
      ob[(w * 16 + quad * 4 + r) * 72 + dt * 16 + l15] =
          f2bf(oacc[dt][r] / lq[r]);
  __syncthreads();
  const int b = bh >> 4, h = bh & 15;
  for (int p2 = 0; p2 < 2; p2++) {
    const int idx = p2 * 256 + tid;
    const int row = idx >> 3;
    const int c = (idx & 7) * 8;
    *(u16x8*)&AO[(size_t)(b * NS + q0 + row) * ND + h * 64 + c] =
        *(const u16x8*)&ob[row * 72 + c];
  }
}

extern "C" void kernel_launch(void* const* d_in, const int* in_sizes, int n_in,
                              void* d_out, int out_size, void* d_ws, size_t ws_size,
                              hipStream_t stream) {
  const float* x = (const float*)d_in[0];   // fp32 [B][S][D]
  const int* tp = (const int*)d_in[1];
  const float* Wq = (const float*)d_in[2];  // fp32 [D][D]
  const float* Wk = (const float*)d_in[3];
  const float* Wv = (const float*)d_in[4];
  const float* Wo = (const float*)d_in[5];

  const size_t NE = (size_t)NB * NS * ND;   // 8,388,608
  const int NW = ND * ND;                   // 1,048,576
  u16* Qb = (u16*)d_ws;
  u16* Kb = Qb + NE;
  u16* Vb = Kb + NE;
  u16* Xbf = Vb + NE;       // x as bf16; reused as AO after QKV GEMM
  u16* Wbf = Xbf + NE;      // 4 weight matrices bf16
  // total ws: (4*NE + 4*NW)*2 = 75.5 MB

  dim3 blk(256);
  // one-time fp32 -> bf16 conversions
  cvt_bf16<<<dim3((unsigned)(NE / 2048)), blk, 0, stream>>>(x, Xbf, (int)NE);
  cvt_bf16<<<dim3(NW / 2048), blk, 0, stream>>>(Wq, Wbf + 0 * (size_t)NW, NW);
  cvt_bf16<<<dim3(NW / 2048), blk, 0, stream>>>(Wk, Wbf + 1 * (size_t)NW, NW);
  cvt_bf16<<<dim3(NW / 2048), blk, 0, stream>>>(Wv, Wbf + 2 * (size_t)NW, NW);
  cvt_bf16<<<dim3(NW / 2048), blk, 0, stream>>>(Wo, Wbf + 3 * (size_t)NW, NW);
  // QKV projections + fused RoPE (Q pre-scaled by 1/8*log2e)
  gemm_qkv<<<dim3(64, 8, 3), blk, 0, stream>>>(
      Xbf, Wbf, Wbf + (size_t)NW, Wbf + 2 * (size_t)NW, Qb, Kb, Vb, tp, 0);
  // causal MFMA flash attention -> AO (= Xbf, bf16 row-major)
  attn<<<dim3(NS / 64, NB * NH), blk, 0, stream>>>(Qb, Kb, Vb, Xbf);
  // output projection -> d_out as fp32
  gemm_qkv<<<dim3(64, 8, 1), blk, 0, stream>>>(
      Xbf, Wbf + 3 * (size_t)NW, Wbf + 3 * (size_t)NW, Wbf + 3 * (size_t)NW,
      d_out, d_out, d_out, tp, 3);
}